// Round 14
// baseline (502.716 us; speedup 1.0000x reference)
//
#include <hip/hip_runtime.h>
#include <hip/hip_bf16.h>

typedef unsigned short u16;
typedef __bf16 bf16x8 __attribute__((ext_vector_type(8)));
typedef float f32x4 __attribute__((ext_vector_type(4)));

#define NN 100000
#define NE 800000
#define NGRAPH 1024
#define KREP 10
#define HD 512
#define MQ 10240
#define FCN 256
#define EPS 1e-5f

static __device__ __forceinline__ float bf2f(u16 u) {
  return __uint_as_float(((unsigned int)u) << 16);
}
static __device__ __forceinline__ u16 f2bf(float f) {
  __hip_bfloat16 h = __float2bfloat16(f);
  u16 u; __builtin_memcpy(&u, &h, 2); return u;
}
static __device__ __forceinline__ void gadd(float* p, float v) { unsafeAtomicAdd(p, v); }

// ---- fp8 e4m3 pack/unpack (native v_cvt on gfx950) ----
static __device__ __forceinline__ unsigned int pk4_fp8(float a, float b, float c, float d) {
  int w = __builtin_amdgcn_cvt_pk_fp8_f32(a, b, 0, false);
  w = __builtin_amdgcn_cvt_pk_fp8_f32(c, d, w, true);
  return (unsigned int)w;
}
static __device__ __forceinline__ void unpk4_fp8(unsigned int w, float f[4]) {
  auto p01 = __builtin_amdgcn_cvt_pk_f32_fp8((int)w, false);
  auto p23 = __builtin_amdgcn_cvt_pk_f32_fp8((int)w, true);
  f[0] = p01[0]; f[1] = p01[1]; f[2] = p23[0]; f[3] = p23[1];
}

template <int BNIN>
static __device__ __forceinline__ void accw8(uint2 r, float a[8], const float sc[8], const float sh[8],
                                             float w) {
  float f[8];
  unpk4_fp8(r.x, f);
  unpk4_fp8(r.y, f + 4);
#pragma unroll
  for (int j = 0; j < 8; j++) {
    float v = f[j];
    if (BNIN) v = fmaxf(v * sc[j] + sh[j], 0.f);
    a[j] = fmaf(v, w, a[j]);
  }
}

// ---------------- K1: h0 init (blocks <1563) + weight cvt + ne cvt + deg count ----------------
__global__ __launch_bounds__(256) void k_initc(const float* __restrict__ nh, const float* __restrict__ w,
                                               const float* __restrict__ bi, unsigned char* __restrict__ h8,
                                               const float* __restrict__ w1, const float* __restrict__ w2,
                                               const float* __restrict__ w3, u16* __restrict__ Wb,
                                               const float* __restrict__ ne, u16* __restrict__ Ane,
                                               const int* __restrict__ dst, int* __restrict__ deg) {
  int t = threadIdx.x;
  int b = blockIdx.x;
  if (b >= 1563) {
    int idx = (b - 1563) * 256 + t;
    if (idx < 131072) {
      int i4 = idx * 4;
      const float* src; int off;
      if (i4 < 393216) { src = w1; off = i4; }
      else if (i4 < 458752) { src = w2; off = i4 - 393216; }
      else { src = w3; off = i4 - 458752; }
      float4 v = *(const float4*)&src[off];
      ushort4 o; o.x = f2bf(v.x); o.y = f2bf(v.y); o.z = f2bf(v.z); o.w = f2bf(v.w);
      *(ushort4*)&Wb[i4] = o;
    } else if (idx < 131072 + 1310720) {
      int j = idx - 131072;
      int i4 = j * 4;
      float4 v = *(const float4*)&ne[i4];
      ushort4 o; o.x = f2bf(v.x); o.y = f2bf(v.y); o.z = f2bf(v.z); o.w = f2bf(v.w);
      *(ushort4*)&Ane[i4] = o;
    } else {
      int j = idx - (131072 + 1310720);
      if (j < NE) atomicAdd(&deg[dst[j]], 1);
    }
    return;
  }
  __shared__ float als[64 * 20];
  float wr0[20], wr1[20];
#pragma unroll
  for (int k = 0; k < 20; k++) {
    float2 wv = *(const float2*)&w[k * 512 + t * 2];
    wr0[k] = wv.x; wr1[k] = wv.y;
  }
  int v0 = b * 64;
  for (int i = t; i < 64 * 20; i += 256) {
    size_t gi = (size_t)v0 * 20 + i;
    als[i] = (gi < (size_t)NN * 20) ? nh[gi] : 0.0f;
  }
  __syncthreads();
  float b0 = bi[t * 2], b1 = bi[t * 2 + 1];
  u16* h16 = (u16*)h8;
  for (int ni = 0; ni < 64; ni++) {
    int v = v0 + ni; if (v >= NN) break;
    float s0 = b0, s1 = b1;
#pragma unroll
    for (int k4 = 0; k4 < 5; k4++) {
      float4 av = *(const float4*)&als[ni * 20 + k4 * 4];
      s0 += av.x * wr0[k4 * 4 + 0]; s1 += av.x * wr1[k4 * 4 + 0];
      s0 += av.y * wr0[k4 * 4 + 1]; s1 += av.y * wr1[k4 * 4 + 1];
      s0 += av.z * wr0[k4 * 4 + 2]; s1 += av.z * wr1[k4 * 4 + 2];
      s0 += av.w * wr0[k4 * 4 + 3]; s1 += av.w * wr1[k4 * 4 + 3];
    }
    unsigned int pk = (unsigned int)__builtin_amdgcn_cvt_pk_fp8_f32(s0, s1, 0, false);
    h16[v * 256 + t] = (u16)(pk & 0xffffu);
  }
}

// ---------------- CSR build ----------------
__global__ __launch_bounds__(256) void k_scan_part(const int* __restrict__ deg, int* __restrict__ part) {
  __shared__ int ls[256];
  int t = threadIdx.x; int base = blockIdx.x * 1024;
  int s = 0;
  for (int i = t; i < 1024; i += 256) { int idx = base + i; if (idx < NN) s += deg[idx]; }
  ls[t] = s; __syncthreads();
  for (int o = 128; o > 0; o >>= 1) { if (t < o) ls[t] += ls[t + o]; __syncthreads(); }
  if (t == 0) part[blockIdx.x] = ls[0];
}

__global__ void k_scan_mid(int* part, int nb, int* offs) {
  __shared__ int ls[128];
  int t = threadIdx.x;
  if (t < nb) ls[t] = part[t];
  __syncthreads();
  if (t == 0) {
    int run = 0;
    for (int i = 0; i < nb; i++) { int v = ls[i]; ls[i] = run; run += v; }
  }
  __syncthreads();
  if (t < nb) part[t] = ls[t];
  if (t == 0) offs[NN] = NE;
}

__global__ __launch_bounds__(256) void k_scan_apply(const int* __restrict__ deg, const int* __restrict__ part,
                                                    int* __restrict__ offs, int* __restrict__ cursor) {
  __shared__ int ls[256];
  int t = threadIdx.x; int base = blockIdx.x * 1024 + t * 4;
  int v[4]; int s = 0;
#pragma unroll
  for (int j = 0; j < 4; j++) { int idx = base + j; v[j] = (idx < NN) ? deg[idx] : 0; s += v[j]; }
  ls[t] = s; __syncthreads();
  for (int o = 1; o < 256; o <<= 1) {
    int x = (t >= o) ? ls[t - o] : 0;
    __syncthreads();
    ls[t] += x;
    __syncthreads();
  }
  int excl = ls[t] - s + part[blockIdx.x];
#pragma unroll
  for (int j = 0; j < 4; j++) {
    int idx = base + j;
    if (idx < NN) { offs[idx] = excl; cursor[idx] = excl; }
    excl += v[j];
  }
}

__global__ void k_fill(const int* __restrict__ src, const int* __restrict__ dst,
                       int* __restrict__ cursor, int* __restrict__ nsrc) {
  int i = blockIdx.x * 256 + threadIdx.x;
  if (i < 32) nsrc[NE + i] = 0;   // zero padding for gin's unconditional batch reads
  if (i < NE) { int p = atomicAdd(&cursor[dst[i]], 1); nsrc[p] = src[i]; }
}

// ---------------- K5: GIN mean gather — fp8 rows, scalarized, 8-deep clamped batches ----------------
// BNIN=1: relu(bn(x)) applied per input element. OUT8=1: write fp8, else bf16.
template <int BNIN, int OUT8>
__global__ __launch_bounds__(256) void k_gin(const unsigned char* __restrict__ hin, const int* __restrict__ offs,
                                             const int* __restrict__ nsrc,
                                             const float* __restrict__ ics, const float* __restrict__ icq,
                                             const float* __restrict__ ig, const float* __restrict__ ibe,
                                             void* __restrict__ xout, float* __restrict__ cs,
                                             float* __restrict__ cq) {
  __shared__ float redS[4][512];
  __shared__ float redQ[4][512];
  int t = threadIdx.x, wid = t >> 6, lane = t & 63;
  int c0 = lane * 8;
  float sc[8], sh[8];
  if (BNIN) {
    const float invn = 1.0f / (float)NN;
#pragma unroll
    for (int j = 0; j < 8; j++) {
      float m = ics[c0 + j] * invn;
      float var = icq[c0 + j] * invn - m * m;
      sc[j] = ig[c0 + j] * rsqrtf(var + EPS);
      sh[j] = ibe[c0 + j] - m * sc[j];
    }
  }
  float s[8] = {0, 0, 0, 0, 0, 0, 0, 0}, q[8] = {0, 0, 0, 0, 0, 0, 0, 0};
  int l7 = lane & 7;
  for (int vb = blockIdx.x * 4; vb < NN; vb += gridDim.x * 4) {
    int v = __builtin_amdgcn_readfirstlane(vb + wid);
    if (v >= NN) continue;
    int e0 = __builtin_amdgcn_readfirstlane(offs[v]);
    int e1 = __builtin_amdgcn_readfirstlane(offs[v + 1]);
    uint2 hv = *(const uint2*)&hin[(size_t)v * 512 + c0];
    float a[8] = {0, 0, 0, 0, 0, 0, 0, 0};
    int myn = nsrc[e0 + l7];   // lanes 0..7 carry the batch's indices (padded read OK)
    for (int e = e0; e < e1; e += 8) {
      int mynext = nsrc[e + 8 + l7];   // unconditional, padded; in flight during accumulate
      int si0 = __builtin_amdgcn_readlane(myn, 0);
      int si1 = __builtin_amdgcn_readlane(myn, 1);
      int si2 = __builtin_amdgcn_readlane(myn, 2);
      int si3 = __builtin_amdgcn_readlane(myn, 3);
      int si4 = __builtin_amdgcn_readlane(myn, 4);
      int si5 = __builtin_amdgcn_readlane(myn, 5);
      int si6 = __builtin_amdgcn_readlane(myn, 6);
      int si7 = __builtin_amdgcn_readlane(myn, 7);
      // scalar clamp: out-of-degree slots re-load si0's row (L1 hit), masked by weight 0
      int sj[8];
      sj[0] = si0;
      sj[1] = (e + 1 < e1) ? si1 : si0;
      sj[2] = (e + 2 < e1) ? si2 : si0;
      sj[3] = (e + 3 < e1) ? si3 : si0;
      sj[4] = (e + 4 < e1) ? si4 : si0;
      sj[5] = (e + 5 < e1) ? si5 : si0;
      sj[6] = (e + 6 < e1) ? si6 : si0;
      sj[7] = (e + 7 < e1) ? si7 : si0;
      uint2 r[8];
#pragma unroll
      for (int j = 0; j < 8; j++) r[j] = *(const uint2*)&hin[(size_t)sj[j] * 512 + c0];
      accw8<BNIN>(r[0], a, sc, sh, 1.0f);
#pragma unroll
      for (int j = 1; j < 8; j++) accw8<BNIN>(r[j], a, sc, sh, (e + j < e1) ? 1.0f : 0.0f);
      myn = mynext;
    }
    float inv = 1.0f / fmaxf((float)(e1 - e0), 1.0f);
    float hf[8];
    unpk4_fp8(hv.x, hf);
    unpk4_fp8(hv.y, hf + 4);
    float xv[8];
#pragma unroll
    for (int j = 0; j < 8; j++) {
      float h0 = hf[j];
      if (BNIN) h0 = fmaxf(h0 * sc[j] + sh[j], 0.f);
      xv[j] = h0 + a[j] * inv;
    }
    if (OUT8) {
      uint2 o;
      o.x = pk4_fp8(xv[0], xv[1], xv[2], xv[3]);
      o.y = pk4_fp8(xv[4], xv[5], xv[6], xv[7]);
      *(uint2*)&((unsigned char*)xout)[(size_t)v * 512 + c0] = o;
      float rf[8];
      unpk4_fp8(o.x, rf);
      unpk4_fp8(o.y, rf + 4);
#pragma unroll
      for (int j = 0; j < 8; j++) { s[j] += rf[j]; q[j] += rf[j] * rf[j]; }
    } else {
      unsigned int ho[4];
#pragma unroll
      for (int k = 0; k < 4; k++) {
        u16 b0 = f2bf(xv[2 * k]), b1 = f2bf(xv[2 * k + 1]);
        ho[k] = ((unsigned int)b1 << 16) | (unsigned int)b0;
        float x0 = bf2f(b0), x1 = bf2f(b1);
        s[2 * k] += x0; q[2 * k] += x0 * x0;
        s[2 * k + 1] += x1; q[2 * k + 1] += x1 * x1;
      }
      *(int4*)&((u16*)xout)[(size_t)v * HD + c0] = *(int4*)ho;
    }
  }
#pragma unroll
  for (int j = 0; j < 8; j++) { redS[wid][c0 + j] = s[j]; redQ[wid][c0 + j] = q[j]; }
  __syncthreads();
  for (int i = t; i < 512; i += 256) {
    float ts = redS[0][i] + redS[1][i] + redS[2][i] + redS[3][i];
    float tq = redQ[0][i] + redQ[1][i] + redQ[2][i] + redQ[3][i];
    gadd(&cs[i], ts);
    gadd(&cq[i], tq);
  }
}

// ---------------- K7: per-graph mean pooling with fused BN2+ReLU (fp8 input) ----------------
__global__ __launch_bounds__(256) void k_poolbn(const unsigned char* __restrict__ h8, const int* __restrict__ ngr,
                                                const float* __restrict__ ics, const float* __restrict__ icq,
                                                const float* __restrict__ ig, const float* __restrict__ ibe,
                                                u16* __restrict__ qemb) {
  __shared__ float red[4][512];
  int g = blockIdx.x; int t = threadIdx.x, wid = t >> 6, lane = t & 63;
  int c0 = lane * 8;
  const float invn = 1.0f / (float)NN;
  float sc[8], sh[8];
#pragma unroll
  for (int j = 0; j < 8; j++) {
    float m = ics[c0 + j] * invn;
    float var = icq[c0 + j] * invn - m * m;
    sc[j] = ig[c0 + j] * rsqrtf(var + EPS);
    sh[j] = ibe[c0 + j] - m * sc[j];
  }
  int lo = 0, hi = NN;
  while (lo < hi) { int mid = (lo + hi) >> 1; if (ngr[mid] < g) lo = mid + 1; else hi = mid; }
  int s0_ = lo;
  hi = NN;
  while (lo < hi) { int mid = (lo + hi) >> 1; if (ngr[mid] < g + 1) lo = mid + 1; else hi = mid; }
  int e_ = lo;
  float a[8] = {0, 0, 0, 0, 0, 0, 0, 0};
  for (int v = s0_ + wid; v < e_; v += 4) {
    uint2 r = *(const uint2*)&h8[(size_t)v * 512 + c0];
    float f[8];
    unpk4_fp8(r.x, f);
    unpk4_fp8(r.y, f + 4);
#pragma unroll
    for (int j = 0; j < 8; j++) a[j] += fmaxf(f[j] * sc[j] + sh[j], 0.f);
  }
#pragma unroll
  for (int j = 0; j < 8; j++) red[wid][c0 + j] = a[j];
  __syncthreads();
  float inv = 1.0f / fmaxf((float)(e_ - s0_), 1.0f);
  int cc = t * 2;
  float r0 = (red[0][cc] + red[1][cc] + red[2][cc] + red[3][cc]) * inv;
  float r1 = (red[0][cc + 1] + red[1][cc + 1] + red[2][cc + 1] + red[3][cc + 1]) * inv;
  unsigned int o = ((unsigned int)f2bf(r1) << 16) | (unsigned int)f2bf(r0);
  *(unsigned int*)&qemb[(size_t)g * HD + cc] = o;
}

// ---------------- GEMM C[M,256] = A[M,Kd] @ W[Kd,256](bf16)
// MODE 0: out f32 = acc + bias (no stats);  MODE 1: out bf16 + stats;  MODE 2: out bf16 + rowadd + stats
// BNA 1: relu(bn(A)) during staging (Kd==256, ASRC 0)
// ASRC 0: A = bf16[M][Kd];  ASRC 2: A cols<512 from qemb(bf16), cols>=512 from Apg(f32)
template <int MODE, int BNA, int ASRC>
__global__ __launch_bounds__(256) void k_gemm(const void* __restrict__ A, const float* __restrict__ Apg,
                                              const u16* __restrict__ W,
                                              const float* __restrict__ bias, const float* __restrict__ rowadd,
                                              const float* __restrict__ bns, const float* __restrict__ bnq,
                                              const float* __restrict__ bng, const float* __restrict__ bnb,
                                              void* __restrict__ Cout,
                                              float* __restrict__ cs, float* __restrict__ cq, int Kd) {
  __shared__ __align__(16) u16 Als[64][40];
  __shared__ __align__(16) u16 Bls[64][40];
  __shared__ float redS[64], redQ[64];
  __shared__ float scK[256], shK[256];
  int t = threadIdx.x; int wid = t >> 6; int lane = t & 63;
  int m0 = blockIdx.x * 64, n0 = blockIdx.y * 64;
  int wr = wid >> 1, wc = wid & 1;
  if (MODE != 0 && t < 64) { redS[t] = 0.f; redQ[t] = 0.f; }
  if (BNA) {
    const float invn = 1.0f / (float)MQ;
    float m = bns[t] * invn;
    float var = bnq[t] * invn - m * m;
    float scv = bng[t] * rsqrtf(var + EPS);
    scK[t] = scv; shK[t] = bnb[t] - m * scv;
  }
  f32x4 zero = {0.0f, 0.0f, 0.0f, 0.0f};
  f32x4 acc[2][2];
#pragma unroll
  for (int i = 0; i < 2; i++)
#pragma unroll
    for (int j = 0; j < 2; j++) acc[i][j] = zero;
  int ar = t >> 2, akc = (t & 3) * 8;
  int bk = t >> 3, bnc = (t & 7) * 8;
  int row = lane & 15, kc = (lane >> 4) * 8;
  if (BNA) __syncthreads();
  for (int k0 = 0; k0 < Kd; k0 += 32) {
    if (ASRC == 2) {
      int kcol = k0 + akc;
      if (kcol < 512) {
        *(int4*)&Als[ar][akc] = *(const int4*)&((const u16*)A)[(size_t)(m0 + ar) * 512 + kcol];
      } else {
        float4 v0 = *(const float4*)&Apg[(size_t)(m0 + ar) * 512 + kcol - 512];
        float4 v1 = *(const float4*)&Apg[(size_t)(m0 + ar) * 512 + kcol - 512 + 4];
        ushort4 o0, o1;
        o0.x = f2bf(v0.x); o0.y = f2bf(v0.y); o0.z = f2bf(v0.z); o0.w = f2bf(v0.w);
        o1.x = f2bf(v1.x); o1.y = f2bf(v1.y); o1.z = f2bf(v1.z); o1.w = f2bf(v1.w);
        *(ushort4*)&Als[ar][akc] = o0;
        *(ushort4*)&Als[ar][akc + 4] = o1;
      }
    } else if (BNA) {
      union { int4 v; unsigned int w[4]; } av;
      av.v = *(const int4*)&((const u16*)A)[(size_t)(m0 + ar) * Kd + k0 + akc];
      unsigned int o[4];
#pragma unroll
      for (int kk = 0; kk < 4; kk++) {
        int kcol = k0 + akc + 2 * kk;
        float f0 = __uint_as_float(av.w[kk] << 16);
        float f1 = __uint_as_float(av.w[kk] & 0xffff0000u);
        float y0 = fmaxf(f0 * scK[kcol] + shK[kcol], 0.f);
        float y1 = fmaxf(f1 * scK[kcol + 1] + shK[kcol + 1], 0.f);
        o[kk] = ((unsigned int)f2bf(y1) << 16) | (unsigned int)f2bf(y0);
      }
      *(int4*)&Als[ar][akc] = *(int4*)o;
    } else {
      *(int4*)&Als[ar][akc] = *(const int4*)&((const u16*)A)[(size_t)(m0 + ar) * Kd + k0 + akc];
    }
    union { int4 v; u16 u[8]; } bv;
    bv.v = *(const int4*)&W[(size_t)(k0 + bk) * FCN + n0 + bnc];
#pragma unroll
    for (int j = 0; j < 8; j++) Bls[bnc + j][bk] = bv.u[j];
    __syncthreads();
    bf16x8 a0 = *(const bf16x8*)&Als[wr * 32 + row][kc];
    bf16x8 a1 = *(const bf16x8*)&Als[wr * 32 + 16 + row][kc];
    bf16x8 b0 = *(const bf16x8*)&Bls[wc * 32 + row][kc];
    bf16x8 b1 = *(const bf16x8*)&Bls[wc * 32 + 16 + row][kc];
    acc[0][0] = __builtin_amdgcn_mfma_f32_16x16x32_bf16(a0, b0, acc[0][0], 0, 0, 0);
    acc[0][1] = __builtin_amdgcn_mfma_f32_16x16x32_bf16(a0, b1, acc[0][1], 0, 0, 0);
    acc[1][0] = __builtin_amdgcn_mfma_f32_16x16x32_bf16(a1, b0, acc[1][0], 0, 0, 0);
    acc[1][1] = __builtin_amdgcn_mfma_f32_16x16x32_bf16(a1, b1, acc[1][1], 0, 0, 0);
    __syncthreads();
  }
#pragma unroll
  for (int fn = 0; fn < 2; fn++) {
    int cl = wc * 32 + fn * 16 + (lane & 15);
    int col = n0 + cl;
    float bcol = (MODE == 2) ? 0.f : bias[col];
    float sS = 0.f, sQ = 0.f;
#pragma unroll
    for (int fm = 0; fm < 2; fm++) {
#pragma unroll
      for (int r = 0; r < 4; r++) {
        int rr = m0 + wr * 32 + fm * 16 + (lane >> 4) * 4 + r;
        float v = acc[fm][fn][r] + bcol;
        if (MODE == 0) {
          ((float*)Cout)[(size_t)rr * FCN + col] = v;
        } else {
          if (MODE == 2) v += rowadd[(size_t)(rr / KREP) * FCN + col];
          u16 b = f2bf(v);
          ((u16*)Cout)[(size_t)rr * FCN + col] = b;
          float xr = bf2f(b);
          sS += xr; sQ += xr * xr;
        }
      }
    }
    if (MODE != 0) { atomicAdd(&redS[cl], sS); atomicAdd(&redQ[cl], sQ); }
  }
  if (MODE != 0) {
    __syncthreads();
    if (t < 64) { gadd(&cs[n0 + t], redS[t]); gadd(&cq[n0 + t], redQ[t]); }
  }
}

// ---------------- final: BN3 + ReLU -> H3 f32 (output), fused fc4 dot + sigmoid -> preds ----------------
__global__ __launch_bounds__(256) void k_bnfc4(const u16* __restrict__ x, const float* __restrict__ cs,
                                               const float* __restrict__ cq, const float* __restrict__ g,
                                               const float* __restrict__ be, const float* __restrict__ w4,
                                               const float* __restrict__ b4, float* __restrict__ H3,
                                               float* __restrict__ preds) {
  const float invn = 1.0f / (float)MQ;
  int tid = blockIdx.x * 256 + threadIdx.x;
  int r = tid >> 5;
  int c0 = (tid & 31) * 8;
  float sc[8], sh[8];
#pragma unroll
  for (int j = 0; j < 8; j++) {
    float m = cs[c0 + j] * invn;
    float var = cq[c0 + j] * invn - m * m;
    sc[j] = g[c0 + j] * rsqrtf(var + EPS);
    sh[j] = be[c0 + j] - m * sc[j];
  }
  int4 u = *(const int4*)&x[(size_t)r * FCN + c0];
  float y[8];
#pragma unroll
  for (int k = 0; k < 4; k++) {
    unsigned int w = ((unsigned int*)&u)[k];
    y[2 * k]     = fmaxf(__uint_as_float(w << 16) * sc[2 * k] + sh[2 * k], 0.f);
    y[2 * k + 1] = fmaxf(__uint_as_float(w & 0xffff0000u) * sc[2 * k + 1] + sh[2 * k + 1], 0.f);
  }
  float4 o0 = {y[0], y[1], y[2], y[3]}, o1 = {y[4], y[5], y[6], y[7]};
  *(float4*)&H3[(size_t)r * FCN + c0] = o0;
  *(float4*)&H3[(size_t)r * FCN + c0 + 4] = o1;
  float4 w0 = *(const float4*)&w4[c0];
  float4 w1 = *(const float4*)&w4[c0 + 4];
  float dp = y[0] * w0.x + y[1] * w0.y + y[2] * w0.z + y[3] * w0.w +
             y[4] * w1.x + y[5] * w1.y + y[6] * w1.z + y[7] * w1.w;
#pragma unroll
  for (int o = 16; o >= 1; o >>= 1) dp += __shfl_xor(dp, o, 64);
  if ((tid & 31) == 0) preds[r] = 1.0f / (1.0f + expf(-(dp + b4[0])));
}

extern "C" void kernel_launch(void* const* d_in, const int* in_sizes, int n_in,
                              void* d_out, int out_size, void* d_ws, size_t ws_size,
                              hipStream_t stream) {
  const float* node_h = (const float*)d_in[0];
  const float* pg     = (const float*)d_in[1];
  const float* ne     = (const float*)d_in[2];
  const int* src = (const int*)d_in[4];
  const int* dst = (const int*)d_in[5];
  const int* ngr = (const int*)d_in[6];
  const float* w_init = (const float*)d_in[7];
  const float* b_init = (const float*)d_in[8];
  const float* g1  = (const float*)d_in[9];
  const float* be1 = (const float*)d_in[10];
  const float* g2  = (const float*)d_in[11];
  const float* be2 = (const float*)d_in[12];
  const float* w_fc  = (const float*)d_in[13];
  const float* b_fc  = (const float*)d_in[14];
  const float* w_fc2 = (const float*)d_in[15];
  const float* b_fc2 = (const float*)d_in[16];
  const float* w_fc3 = (const float*)d_in[17];
  const float* b_fc3 = (const float*)d_in[18];
  const float* w_fc4 = (const float*)d_in[19];
  const float* b_fc4 = (const float*)d_in[20];
  const float* gb  = (const float*)d_in[21];
  const float* bb  = (const float*)d_in[22];
  const float* gb2 = (const float*)d_in[23];
  const float* bb2 = (const float*)d_in[24];
  const float* gb3 = (const float*)d_in[25];
  const float* bb3 = (const float*)d_in[26];

  char* w = (char*)d_ws;
  unsigned char* hA8 = (unsigned char*)w;                 // [N,512] fp8 h0; reused as x2 fp8
  unsigned char* hX8 = (unsigned char*)(w + 51200000LL);  // [N,512] fp8 x1
  u16* Ane = (u16*)(w + 102400000LL);                     // [MQ,512] bf16
  float* P1 = (float*)(w + 102400000LL + 12582912LL);     // [1024,256] f32
  u16* Wb = (u16*)(w + 150000000LL);                      // 1.05 MB bf16 weights
  u16* X1 = (u16*)(w + 102400000LL + 33554432LL);
  u16* X2 = (u16*)(w + 102400000LL + 50331648LL);
  u16* X3 = (u16*)(w + 102400000LL + 67108864LL);
  size_t off = 204800000LL;
  int* deg = (int*)(w + off); off += 400128;
  float* st = (float*)(w + off); off += 16384;
  int* offs = (int*)(w + off); off += 400128;
  int* cursor = (int*)(w + off); off += 400128;
  int* nsrc = (int*)(w + off); off += 3200128;   // +128B zero padding (written in k_fill)
  int* part = (int*)(w + off); off += 2048;
  u16* qemb = (u16*)(w + off); off += 1048576;

  float *s_g1 = st,        *q_g1 = st + 512;
  float *s_g2 = st + 1024, *q_g2 = st + 1536;
  float *s_f1 = st + 2048, *q_f1 = st + 2304;
  float *s_f2 = st + 2560, *q_f2 = st + 2816;
  float *s_f3 = st + 3072, *q_f3 = st + 3328;

  u16* Wq   = Wb;                 // w_fc rows 0..1023
  u16* Wbot = Wb + 1024 * 256;    // w_fc rows 1024..1535
  u16* Wb2  = Wb + 393216;
  u16* Wb3  = Wb + 458752;

  float* preds = (float*)d_out;
  float* H3 = preds + MQ;

  hipMemsetAsync(deg, 0, 400128 + 16384, stream);

  // initc: 1563 h0 blocks + 512 Wcvt + 5120 necvt + 3125 deg = 10320 blocks
  k_initc<<<10320, 256, 0, stream>>>(node_h, w_init, b_init, hA8, w_fc, w_fc2, w_fc3, Wb, ne, Ane,
                                     dst, deg);
  k_scan_part<<<98, 256, 0, stream>>>(deg, part);
  k_scan_mid<<<1, 128, 0, stream>>>(part, 98, offs);
  k_scan_apply<<<98, 256, 0, stream>>>(deg, part, offs, cursor);
  k_fill<<<(NE + 255) / 256, 256, 0, stream>>>(src, dst, cursor, nsrc);

  // layer 1: x1(fp8) = gin(h0 fp8); stats(g1)
  k_gin<0, 1><<<4096, 256, 0, stream>>>(hA8, offs, nsrc, s_g1, q_g1, g1, be1, (void*)hX8, s_g1, q_g1);
  // layer 2: x2(fp8, reuses h0 buffer) = gin(relu(bn1(x1))); stats(g2)
  k_gin<1, 1><<<4096, 256, 0, stream>>>(hX8, offs, nsrc, s_g1, q_g1, g1, be1, (void*)hA8, s_g2, q_g2);

  // pool over relu(bn2(x2))
  k_poolbn<<<NGRAPH, 256, 0, stream>>>(hA8, ngr, s_g2, q_g2, g2, be2, qemb);

  // P1 = [qemb|pg] @ Wtop + bias
  dim3 gq(16, 4);
  k_gemm<0, 0, 2><<<gq, 256, 0, stream>>>((const void*)qemb, pg, Wq, b_fc, nullptr,
                                          nullptr, nullptr, nullptr, nullptr,
                                          (void*)P1, s_f1, q_f1, 1024);
  dim3 gg(160, 4);
  // X1 = Ane @ Wbot + P1[row/KREP]
  k_gemm<2, 0, 0><<<gg, 256, 0, stream>>>((const void*)Ane, nullptr, Wbot, nullptr, P1,
                                          nullptr, nullptr, nullptr, nullptr,
                                          (void*)X1, s_f1, q_f1, 512);
  // X2 = relu(bn(X1)) @ W2 + b2
  k_gemm<1, 1, 0><<<gg, 256, 0, stream>>>((const void*)X1, nullptr, Wb2, b_fc2, nullptr,
                                          s_f1, q_f1, gb, bb,
                                          (void*)X2, s_f2, q_f2, 256);
  // X3 = relu(bn(X2)) @ W3 + b3
  k_gemm<1, 1, 0><<<gg, 256, 0, stream>>>((const void*)X2, nullptr, Wb3, b_fc3, nullptr,
                                          s_f2, q_f2, gb2, bb2,
                                          (void*)X3, s_f3, q_f3, 256);
  k_bnfc4<<<1280, 256, 0, stream>>>(X3, s_f3, q_f3, gb3, bb3, w_fc4, b_fc4, H3, preds);
}

// Round 15
// 450.759 us; speedup vs baseline: 1.1153x; 1.1153x over previous
//
#include <hip/hip_runtime.h>
#include <hip/hip_bf16.h>

typedef unsigned short u16;
typedef __bf16 bf16x8 __attribute__((ext_vector_type(8)));
typedef float f32x4 __attribute__((ext_vector_type(4)));

#define NN 100000
#define NE 800000
#define NGRAPH 1024
#define KREP 10
#define HD 512
#define MQ 10240
#define FCN 256
#define EPS 1e-5f

static __device__ __forceinline__ float bf2f(u16 u) {
  return __uint_as_float(((unsigned int)u) << 16);
}
static __device__ __forceinline__ u16 f2bf(float f) {
  __hip_bfloat16 h = __float2bfloat16(f);
  u16 u; __builtin_memcpy(&u, &h, 2); return u;
}
static __device__ __forceinline__ void gadd(float* p, float v) { unsafeAtomicAdd(p, v); }

// ---- fp8 e4m3 pack/unpack (native v_cvt on gfx950) ----
static __device__ __forceinline__ unsigned int pk4_fp8(float a, float b, float c, float d) {
  int w = __builtin_amdgcn_cvt_pk_fp8_f32(a, b, 0, false);
  w = __builtin_amdgcn_cvt_pk_fp8_f32(c, d, w, true);
  return (unsigned int)w;
}
static __device__ __forceinline__ void unpk4_fp8(unsigned int w, float f[4]) {
  auto p01 = __builtin_amdgcn_cvt_pk_f32_fp8((int)w, false);
  auto p23 = __builtin_amdgcn_cvt_pk_f32_fp8((int)w, true);
  f[0] = p01[0]; f[1] = p01[1]; f[2] = p23[0]; f[3] = p23[1];
}

template <int BNIN>
static __device__ __forceinline__ void accw8(uint2 r, float a[8], const float sc[8], const float sh[8],
                                             float w) {
  float f[8];
  unpk4_fp8(r.x, f);
  unpk4_fp8(r.y, f + 4);
#pragma unroll
  for (int j = 0; j < 8; j++) {
    float v = f[j];
    if (BNIN) v = fmaxf(v * sc[j] + sh[j], 0.f);
    a[j] = fmaf(v, w, a[j]);
  }
}

// ---------------- K1: h0 init (blocks <1563) + weight cvt + ne cvt + deg count ----------------
__global__ __launch_bounds__(256) void k_initc(const float* __restrict__ nh, const float* __restrict__ w,
                                               const float* __restrict__ bi, unsigned char* __restrict__ h8,
                                               const float* __restrict__ w1, const float* __restrict__ w2,
                                               const float* __restrict__ w3, u16* __restrict__ Wb,
                                               const float* __restrict__ ne, u16* __restrict__ Ane,
                                               const int* __restrict__ dst, int* __restrict__ deg) {
  int t = threadIdx.x;
  int b = blockIdx.x;
  if (b >= 1563) {
    int idx = (b - 1563) * 256 + t;
    if (idx < 131072) {
      int i4 = idx * 4;
      const float* src; int off;
      if (i4 < 393216) { src = w1; off = i4; }
      else if (i4 < 458752) { src = w2; off = i4 - 393216; }
      else { src = w3; off = i4 - 458752; }
      float4 v = *(const float4*)&src[off];
      ushort4 o; o.x = f2bf(v.x); o.y = f2bf(v.y); o.z = f2bf(v.z); o.w = f2bf(v.w);
      *(ushort4*)&Wb[i4] = o;
    } else if (idx < 131072 + 1310720) {
      int j = idx - 131072;
      int i4 = j * 4;
      float4 v = *(const float4*)&ne[i4];
      ushort4 o; o.x = f2bf(v.x); o.y = f2bf(v.y); o.z = f2bf(v.z); o.w = f2bf(v.w);
      *(ushort4*)&Ane[i4] = o;
    } else {
      int j = idx - (131072 + 1310720);
      if (j < NE) atomicAdd(&deg[dst[j]], 1);
    }
    return;
  }
  __shared__ float als[64 * 20];
  float wr0[20], wr1[20];
#pragma unroll
  for (int k = 0; k < 20; k++) {
    float2 wv = *(const float2*)&w[k * 512 + t * 2];
    wr0[k] = wv.x; wr1[k] = wv.y;
  }
  int v0 = b * 64;
  for (int i = t; i < 64 * 20; i += 256) {
    size_t gi = (size_t)v0 * 20 + i;
    als[i] = (gi < (size_t)NN * 20) ? nh[gi] : 0.0f;
  }
  __syncthreads();
  float b0 = bi[t * 2], b1 = bi[t * 2 + 1];
  u16* h16 = (u16*)h8;
  for (int ni = 0; ni < 64; ni++) {
    int v = v0 + ni; if (v >= NN) break;
    float s0 = b0, s1 = b1;
#pragma unroll
    for (int k4 = 0; k4 < 5; k4++) {
      float4 av = *(const float4*)&als[ni * 20 + k4 * 4];
      s0 += av.x * wr0[k4 * 4 + 0]; s1 += av.x * wr1[k4 * 4 + 0];
      s0 += av.y * wr0[k4 * 4 + 1]; s1 += av.y * wr1[k4 * 4 + 1];
      s0 += av.z * wr0[k4 * 4 + 2]; s1 += av.z * wr1[k4 * 4 + 2];
      s0 += av.w * wr0[k4 * 4 + 3]; s1 += av.w * wr1[k4 * 4 + 3];
    }
    unsigned int pk = (unsigned int)__builtin_amdgcn_cvt_pk_fp8_f32(s0, s1, 0, false);
    h16[v * 256 + t] = (u16)(pk & 0xffffu);
  }
}

// ---------------- CSR build ----------------
__global__ __launch_bounds__(256) void k_scan_part(const int* __restrict__ deg, int* __restrict__ part) {
  __shared__ int ls[256];
  int t = threadIdx.x; int base = blockIdx.x * 1024;
  int s = 0;
  for (int i = t; i < 1024; i += 256) { int idx = base + i; if (idx < NN) s += deg[idx]; }
  ls[t] = s; __syncthreads();
  for (int o = 128; o > 0; o >>= 1) { if (t < o) ls[t] += ls[t + o]; __syncthreads(); }
  if (t == 0) part[blockIdx.x] = ls[0];
}

__global__ void k_scan_mid(int* part, int nb, int* offs) {
  __shared__ int ls[128];
  int t = threadIdx.x;
  if (t < nb) ls[t] = part[t];
  __syncthreads();
  if (t == 0) {
    int run = 0;
    for (int i = 0; i < nb; i++) { int v = ls[i]; ls[i] = run; run += v; }
  }
  __syncthreads();
  if (t < nb) part[t] = ls[t];
  if (t == 0) offs[NN] = NE;
}

__global__ __launch_bounds__(256) void k_scan_apply(const int* __restrict__ deg, const int* __restrict__ part,
                                                    int* __restrict__ offs, int* __restrict__ cursor) {
  __shared__ int ls[256];
  int t = threadIdx.x; int base = blockIdx.x * 1024 + t * 4;
  int v[4]; int s = 0;
#pragma unroll
  for (int j = 0; j < 4; j++) { int idx = base + j; v[j] = (idx < NN) ? deg[idx] : 0; s += v[j]; }
  ls[t] = s; __syncthreads();
  for (int o = 1; o < 256; o <<= 1) {
    int x = (t >= o) ? ls[t - o] : 0;
    __syncthreads();
    ls[t] += x;
    __syncthreads();
  }
  int excl = ls[t] - s + part[blockIdx.x];
#pragma unroll
  for (int j = 0; j < 4; j++) {
    int idx = base + j;
    if (idx < NN) { offs[idx] = excl; cursor[idx] = excl; }
    excl += v[j];
  }
}

__global__ void k_fill(const int* __restrict__ src, const int* __restrict__ dst,
                       int* __restrict__ cursor, int* __restrict__ nsrc) {
  int i = blockIdx.x * 256 + threadIdx.x;
  if (i < 32) nsrc[NE + i] = 0;   // zero padding for gin's unconditional batch reads
  if (i < NE) { int p = atomicAdd(&cursor[dst[i]], 1); nsrc[p] = src[i]; }
}

// ---------------- K5: GIN mean gather — fp8 rows, scalarized, 8-deep clamped batches ----------------
// BNIN=1: relu(bn(x)) applied per input element. OUT8=1: write fp8, else bf16.
template <int BNIN, int OUT8>
__global__ __launch_bounds__(256) void k_gin(const unsigned char* __restrict__ hin, const int* __restrict__ offs,
                                             const int* __restrict__ nsrc,
                                             const float* __restrict__ ics, const float* __restrict__ icq,
                                             const float* __restrict__ ig, const float* __restrict__ ibe,
                                             void* __restrict__ xout, float* __restrict__ cs,
                                             float* __restrict__ cq) {
  __shared__ float redS[4][512];
  __shared__ float redQ[4][512];
  int t = threadIdx.x, wid = t >> 6, lane = t & 63;
  int c0 = lane * 8;
  float sc[8], sh[8];
  if (BNIN) {
    const float invn = 1.0f / (float)NN;
#pragma unroll
    for (int j = 0; j < 8; j++) {
      float m = ics[c0 + j] * invn;
      float var = icq[c0 + j] * invn - m * m;
      sc[j] = ig[c0 + j] * rsqrtf(var + EPS);
      sh[j] = ibe[c0 + j] - m * sc[j];
    }
  }
  float s[8] = {0, 0, 0, 0, 0, 0, 0, 0}, q[8] = {0, 0, 0, 0, 0, 0, 0, 0};
  int l7 = lane & 7;
  for (int vb = blockIdx.x * 4; vb < NN; vb += gridDim.x * 4) {
    int v = __builtin_amdgcn_readfirstlane(vb + wid);
    if (v >= NN) continue;
    int e0 = __builtin_amdgcn_readfirstlane(offs[v]);
    int e1 = __builtin_amdgcn_readfirstlane(offs[v + 1]);
    uint2 hv = *(const uint2*)&hin[(size_t)v * 512 + c0];
    float a[8] = {0, 0, 0, 0, 0, 0, 0, 0};
    int myn = nsrc[e0 + l7];   // lanes 0..7 carry the batch's indices (padded read OK)
    for (int e = e0; e < e1; e += 8) {
      int mynext = nsrc[e + 8 + l7];   // unconditional, padded; in flight during accumulate
      int si0 = __builtin_amdgcn_readlane(myn, 0);
      int si1 = __builtin_amdgcn_readlane(myn, 1);
      int si2 = __builtin_amdgcn_readlane(myn, 2);
      int si3 = __builtin_amdgcn_readlane(myn, 3);
      int si4 = __builtin_amdgcn_readlane(myn, 4);
      int si5 = __builtin_amdgcn_readlane(myn, 5);
      int si6 = __builtin_amdgcn_readlane(myn, 6);
      int si7 = __builtin_amdgcn_readlane(myn, 7);
      // scalar clamp: out-of-degree slots re-load si0's row (L1 hit), masked by weight 0
      int sj[8];
      sj[0] = si0;
      sj[1] = (e + 1 < e1) ? si1 : si0;
      sj[2] = (e + 2 < e1) ? si2 : si0;
      sj[3] = (e + 3 < e1) ? si3 : si0;
      sj[4] = (e + 4 < e1) ? si4 : si0;
      sj[5] = (e + 5 < e1) ? si5 : si0;
      sj[6] = (e + 6 < e1) ? si6 : si0;
      sj[7] = (e + 7 < e1) ? si7 : si0;
      uint2 r[8];
#pragma unroll
      for (int j = 0; j < 8; j++) r[j] = *(const uint2*)&hin[(size_t)sj[j] * 512 + c0];
      accw8<BNIN>(r[0], a, sc, sh, 1.0f);
#pragma unroll
      for (int j = 1; j < 8; j++) accw8<BNIN>(r[j], a, sc, sh, (e + j < e1) ? 1.0f : 0.0f);
      myn = mynext;
    }
    float inv = 1.0f / fmaxf((float)(e1 - e0), 1.0f);
    float hf[8];
    unpk4_fp8(hv.x, hf);
    unpk4_fp8(hv.y, hf + 4);
    float xv[8];
#pragma unroll
    for (int j = 0; j < 8; j++) {
      float h0 = hf[j];
      if (BNIN) h0 = fmaxf(h0 * sc[j] + sh[j], 0.f);
      xv[j] = h0 + a[j] * inv;
    }
    if (OUT8) {
      uint2 o;
      o.x = pk4_fp8(xv[0], xv[1], xv[2], xv[3]);
      o.y = pk4_fp8(xv[4], xv[5], xv[6], xv[7]);
      *(uint2*)&((unsigned char*)xout)[(size_t)v * 512 + c0] = o;
      float rf[8];
      unpk4_fp8(o.x, rf);
      unpk4_fp8(o.y, rf + 4);
#pragma unroll
      for (int j = 0; j < 8; j++) { s[j] += rf[j]; q[j] += rf[j] * rf[j]; }
    } else {
      unsigned int ho[4];
#pragma unroll
      for (int k = 0; k < 4; k++) {
        u16 b0 = f2bf(xv[2 * k]), b1 = f2bf(xv[2 * k + 1]);
        ho[k] = ((unsigned int)b1 << 16) | (unsigned int)b0;
        float x0 = bf2f(b0), x1 = bf2f(b1);
        s[2 * k] += x0; q[2 * k] += x0 * x0;
        s[2 * k + 1] += x1; q[2 * k + 1] += x1 * x1;
      }
      *(int4*)&((u16*)xout)[(size_t)v * HD + c0] = *(int4*)ho;
    }
  }
#pragma unroll
  for (int j = 0; j < 8; j++) { redS[wid][c0 + j] = s[j]; redQ[wid][c0 + j] = q[j]; }
  __syncthreads();
  for (int i = t; i < 512; i += 256) {
    float ts = redS[0][i] + redS[1][i] + redS[2][i] + redS[3][i];
    float tq = redQ[0][i] + redQ[1][i] + redQ[2][i] + redQ[3][i];
    gadd(&cs[i], ts);
    gadd(&cq[i], tq);
  }
}

// ---------------- K7: per-graph mean pooling with fused BN2+ReLU (fp8 input) ----------------
__global__ __launch_bounds__(256) void k_poolbn(const unsigned char* __restrict__ h8, const int* __restrict__ ngr,
                                                const float* __restrict__ ics, const float* __restrict__ icq,
                                                const float* __restrict__ ig, const float* __restrict__ ibe,
                                                u16* __restrict__ qemb) {
  __shared__ float red[4][512];
  int g = blockIdx.x; int t = threadIdx.x, wid = t >> 6, lane = t & 63;
  int c0 = lane * 8;
  const float invn = 1.0f / (float)NN;
  float sc[8], sh[8];
#pragma unroll
  for (int j = 0; j < 8; j++) {
    float m = ics[c0 + j] * invn;
    float var = icq[c0 + j] * invn - m * m;
    sc[j] = ig[c0 + j] * rsqrtf(var + EPS);
    sh[j] = ibe[c0 + j] - m * sc[j];
  }
  int lo = 0, hi = NN;
  while (lo < hi) { int mid = (lo + hi) >> 1; if (ngr[mid] < g) lo = mid + 1; else hi = mid; }
  int s0_ = lo;
  hi = NN;
  while (lo < hi) { int mid = (lo + hi) >> 1; if (ngr[mid] < g + 1) lo = mid + 1; else hi = mid; }
  int e_ = lo;
  float a[8] = {0, 0, 0, 0, 0, 0, 0, 0};
  for (int v = s0_ + wid; v < e_; v += 4) {
    uint2 r = *(const uint2*)&h8[(size_t)v * 512 + c0];
    float f[8];
    unpk4_fp8(r.x, f);
    unpk4_fp8(r.y, f + 4);
#pragma unroll
    for (int j = 0; j < 8; j++) a[j] += fmaxf(f[j] * sc[j] + sh[j], 0.f);
  }
#pragma unroll
  for (int j = 0; j < 8; j++) red[wid][c0 + j] = a[j];
  __syncthreads();
  float inv = 1.0f / fmaxf((float)(e_ - s0_), 1.0f);
  int cc = t * 2;
  float r0 = (red[0][cc] + red[1][cc] + red[2][cc] + red[3][cc]) * inv;
  float r1 = (red[0][cc + 1] + red[1][cc + 1] + red[2][cc + 1] + red[3][cc + 1]) * inv;
  unsigned int o = ((unsigned int)f2bf(r1) << 16) | (unsigned int)f2bf(r0);
  *(unsigned int*)&qemb[(size_t)g * HD + cc] = o;
}

// ---------------- GEMM C[M,256] = A[M,Kd] @ W[Kd,256](bf16)
// MODE 0: out f32 = acc + bias (no stats);  MODE 1: out bf16 + stats;  MODE 2: out bf16 + rowadd + stats
// BNA 1: relu(bn(A)) during staging (Kd==256, ASRC 0)
// ASRC 0: A = bf16[M][Kd];  ASRC 2: A cols<512 from qemb(bf16), cols>=512 from Apg(f32)
template <int MODE, int BNA, int ASRC>
__global__ __launch_bounds__(256) void k_gemm(const void* __restrict__ A, const float* __restrict__ Apg,
                                              const u16* __restrict__ W,
                                              const float* __restrict__ bias, const float* __restrict__ rowadd,
                                              const float* __restrict__ bns, const float* __restrict__ bnq,
                                              const float* __restrict__ bng, const float* __restrict__ bnb,
                                              void* __restrict__ Cout,
                                              float* __restrict__ cs, float* __restrict__ cq, int Kd) {
  __shared__ __align__(16) u16 Als[64][40];
  __shared__ __align__(16) u16 Bls[64][40];
  __shared__ float redS[64], redQ[64];
  __shared__ float scK[256], shK[256];
  int t = threadIdx.x; int wid = t >> 6; int lane = t & 63;
  int m0 = blockIdx.x * 64, n0 = blockIdx.y * 64;
  int wr = wid >> 1, wc = wid & 1;
  if (MODE != 0 && t < 64) { redS[t] = 0.f; redQ[t] = 0.f; }
  if (BNA) {
    const float invn = 1.0f / (float)MQ;
    float m = bns[t] * invn;
    float var = bnq[t] * invn - m * m;
    float scv = bng[t] * rsqrtf(var + EPS);
    scK[t] = scv; shK[t] = bnb[t] - m * scv;
  }
  f32x4 zero = {0.0f, 0.0f, 0.0f, 0.0f};
  f32x4 acc[2][2];
#pragma unroll
  for (int i = 0; i < 2; i++)
#pragma unroll
    for (int j = 0; j < 2; j++) acc[i][j] = zero;
  int ar = t >> 2, akc = (t & 3) * 8;
  int bk = t >> 3, bnc = (t & 7) * 8;
  int row = lane & 15, kc = (lane >> 4) * 8;
  if (BNA) __syncthreads();
  for (int k0 = 0; k0 < Kd; k0 += 32) {
    if (ASRC == 2) {
      int kcol = k0 + akc;
      if (kcol < 512) {
        *(int4*)&Als[ar][akc] = *(const int4*)&((const u16*)A)[(size_t)(m0 + ar) * 512 + kcol];
      } else {
        float4 v0 = *(const float4*)&Apg[(size_t)(m0 + ar) * 512 + kcol - 512];
        float4 v1 = *(const float4*)&Apg[(size_t)(m0 + ar) * 512 + kcol - 512 + 4];
        ushort4 o0, o1;
        o0.x = f2bf(v0.x); o0.y = f2bf(v0.y); o0.z = f2bf(v0.z); o0.w = f2bf(v0.w);
        o1.x = f2bf(v1.x); o1.y = f2bf(v1.y); o1.z = f2bf(v1.z); o1.w = f2bf(v1.w);
        *(ushort4*)&Als[ar][akc] = o0;
        *(ushort4*)&Als[ar][akc + 4] = o1;
      }
    } else if (BNA) {
      union { int4 v; unsigned int w[4]; } av;
      av.v = *(const int4*)&((const u16*)A)[(size_t)(m0 + ar) * Kd + k0 + akc];
      unsigned int o[4];
#pragma unroll
      for (int kk = 0; kk < 4; kk++) {
        int kcol = k0 + akc + 2 * kk;
        float f0 = __uint_as_float(av.w[kk] << 16);
        float f1 = __uint_as_float(av.w[kk] & 0xffff0000u);
        float y0 = fmaxf(f0 * scK[kcol] + shK[kcol], 0.f);
        float y1 = fmaxf(f1 * scK[kcol + 1] + shK[kcol + 1], 0.f);
        o[kk] = ((unsigned int)f2bf(y1) << 16) | (unsigned int)f2bf(y0);
      }
      *(int4*)&Als[ar][akc] = *(int4*)o;
    } else {
      *(int4*)&Als[ar][akc] = *(const int4*)&((const u16*)A)[(size_t)(m0 + ar) * Kd + k0 + akc];
    }
    union { int4 v; u16 u[8]; } bv;
    bv.v = *(const int4*)&W[(size_t)(k0 + bk) * FCN + n0 + bnc];
#pragma unroll
    for (int j = 0; j < 8; j++) Bls[bnc + j][bk] = bv.u[j];
    __syncthreads();
    bf16x8 a0 = *(const bf16x8*)&Als[wr * 32 + row][kc];
    bf16x8 a1 = *(const bf16x8*)&Als[wr * 32 + 16 + row][kc];
    bf16x8 b0 = *(const bf16x8*)&Bls[wc * 32 + row][kc];
    bf16x8 b1 = *(const bf16x8*)&Bls[wc * 32 + 16 + row][kc];
    acc[0][0] = __builtin_amdgcn_mfma_f32_16x16x32_bf16(a0, b0, acc[0][0], 0, 0, 0);
    acc[0][1] = __builtin_amdgcn_mfma_f32_16x16x32_bf16(a0, b1, acc[0][1], 0, 0, 0);
    acc[1][0] = __builtin_amdgcn_mfma_f32_16x16x32_bf16(a1, b0, acc[1][0], 0, 0, 0);
    acc[1][1] = __builtin_amdgcn_mfma_f32_16x16x32_bf16(a1, b1, acc[1][1], 0, 0, 0);
    __syncthreads();
  }
#pragma unroll
  for (int fn = 0; fn < 2; fn++) {
    int cl = wc * 32 + fn * 16 + (lane & 15);
    int col = n0 + cl;
    float bcol = (MODE == 2) ? 0.f : bias[col];
    float sS = 0.f, sQ = 0.f;
#pragma unroll
    for (int fm = 0; fm < 2; fm++) {
#pragma unroll
      for (int r = 0; r < 4; r++) {
        int rr = m0 + wr * 32 + fm * 16 + (lane >> 4) * 4 + r;
        float v = acc[fm][fn][r] + bcol;
        if (MODE == 0) {
          ((float*)Cout)[(size_t)rr * FCN + col] = v;
        } else {
          if (MODE == 2) v += rowadd[(size_t)(rr / KREP) * FCN + col];
          u16 b = f2bf(v);
          ((u16*)Cout)[(size_t)rr * FCN + col] = b;
          float xr = bf2f(b);
          sS += xr; sQ += xr * xr;
        }
      }
    }
    if (MODE != 0) { atomicAdd(&redS[cl], sS); atomicAdd(&redQ[cl], sQ); }
  }
  if (MODE != 0) {
    __syncthreads();
    if (t < 64) { gadd(&cs[n0 + t], redS[t]); gadd(&cq[n0 + t], redQ[t]); }
  }
}

// ---------------- final: BN3 + ReLU -> H3 f32 (output), fused fc4 dot + sigmoid -> preds ----------------
__global__ __launch_bounds__(256) void k_bnfc4(const u16* __restrict__ x, const float* __restrict__ cs,
                                               const float* __restrict__ cq, const float* __restrict__ g,
                                               const float* __restrict__ be, const float* __restrict__ w4,
                                               const float* __restrict__ b4, float* __restrict__ H3,
                                               float* __restrict__ preds) {
  const float invn = 1.0f / (float)MQ;
  int tid = blockIdx.x * 256 + threadIdx.x;
  int r = tid >> 5;
  int c0 = (tid & 31) * 8;
  float sc[8], sh[8];
#pragma unroll
  for (int j = 0; j < 8; j++) {
    float m = cs[c0 + j] * invn;
    float var = cq[c0 + j] * invn - m * m;
    sc[j] = g[c0 + j] * rsqrtf(var + EPS);
    sh[j] = be[c0 + j] - m * sc[j];
  }
  int4 u = *(const int4*)&x[(size_t)r * FCN + c0];
  float y[8];
#pragma unroll
  for (int k = 0; k < 4; k++) {
    unsigned int w = ((unsigned int*)&u)[k];
    y[2 * k]     = fmaxf(__uint_as_float(w << 16) * sc[2 * k] + sh[2 * k], 0.f);
    y[2 * k + 1] = fmaxf(__uint_as_float(w & 0xffff0000u) * sc[2 * k + 1] + sh[2 * k + 1], 0.f);
  }
  float4 o0 = {y[0], y[1], y[2], y[3]}, o1 = {y[4], y[5], y[6], y[7]};
  *(float4*)&H3[(size_t)r * FCN + c0] = o0;
  *(float4*)&H3[(size_t)r * FCN + c0 + 4] = o1;
  float4 w0 = *(const float4*)&w4[c0];
  float4 w1 = *(const float4*)&w4[c0 + 4];
  float dp = y[0] * w0.x + y[1] * w0.y + y[2] * w0.z + y[3] * w0.w +
             y[4] * w1.x + y[5] * w1.y + y[6] * w1.z + y[7] * w1.w;
#pragma unroll
  for (int o = 16; o >= 1; o >>= 1) dp += __shfl_xor(dp, o, 64);
  if ((tid & 31) == 0) preds[r] = 1.0f / (1.0f + expf(-(dp + b4[0])));
}

extern "C" void kernel_launch(void* const* d_in, const int* in_sizes, int n_in,
                              void* d_out, int out_size, void* d_ws, size_t ws_size,
                              hipStream_t stream) {
  const float* node_h = (const float*)d_in[0];
  const float* pg     = (const float*)d_in[1];
  const float* ne     = (const float*)d_in[2];
  const int* src = (const int*)d_in[4];
  const int* dst = (const int*)d_in[5];
  const int* ngr = (const int*)d_in[6];
  const float* w_init = (const float*)d_in[7];
  const float* b_init = (const float*)d_in[8];
  const float* g1  = (const float*)d_in[9];
  const float* be1 = (const float*)d_in[10];
  const float* g2  = (const float*)d_in[11];
  const float* be2 = (const float*)d_in[12];
  const float* w_fc  = (const float*)d_in[13];
  const float* b_fc  = (const float*)d_in[14];
  const float* w_fc2 = (const float*)d_in[15];
  const float* b_fc2 = (const float*)d_in[16];
  const float* w_fc3 = (const float*)d_in[17];
  const float* b_fc3 = (const float*)d_in[18];
  const float* w_fc4 = (const float*)d_in[19];
  const float* b_fc4 = (const float*)d_in[20];
  const float* gb  = (const float*)d_in[21];
  const float* bb  = (const float*)d_in[22];
  const float* gb2 = (const float*)d_in[23];
  const float* bb2 = (const float*)d_in[24];
  const float* gb3 = (const float*)d_in[25];
  const float* bb3 = (const float*)d_in[26];

  char* w = (char*)d_ws;
  unsigned char* hA8 = (unsigned char*)w;                 // [N,512] fp8 h0; reused as x2 fp8
  unsigned char* hX8 = (unsigned char*)(w + 51200000LL);  // [N,512] fp8 x1
  u16* Ane = (u16*)(w + 102400000LL);                     // [MQ,512] bf16
  float* P1 = (float*)(w + 102400000LL + 12582912LL);     // [1024,256] f32
  u16* Wb = (u16*)(w + 150000000LL);                      // 1.05 MB bf16 weights
  u16* X1 = (u16*)(w + 102400000LL + 33554432LL);
  u16* X2 = (u16*)(w + 102400000LL + 50331648LL);
  u16* X3 = (u16*)(w + 102400000LL + 67108864LL);
  size_t off = 204800000LL;
  int* deg = (int*)(w + off); off += 400128;
  float* st = (float*)(w + off); off += 16384;
  int* offs = (int*)(w + off); off += 400128;
  int* cursor = (int*)(w + off); off += 400128;
  int* nsrc = (int*)(w + off); off += 3200128;   // +128B zero padding (written in k_fill)
  int* part = (int*)(w + off); off += 2048;
  u16* qemb = (u16*)(w + off); off += 1048576;

  float *s_g1 = st,        *q_g1 = st + 512;
  float *s_g2 = st + 1024, *q_g2 = st + 1536;
  float *s_f1 = st + 2048, *q_f1 = st + 2304;
  float *s_f2 = st + 2560, *q_f2 = st + 2816;
  float *s_f3 = st + 3072, *q_f3 = st + 3328;

  u16* Wq   = Wb;                 // w_fc rows 0..1023
  u16* Wbot = Wb + 1024 * 256;    // w_fc rows 1024..1535
  u16* Wb2  = Wb + 393216;
  u16* Wb3  = Wb + 458752;

  float* preds = (float*)d_out;
  float* H3 = preds + MQ;

  hipMemsetAsync(deg, 0, 400128 + 16384, stream);

  // initc: 1563 h0 blocks + 512 Wcvt + 5120 necvt + 3125 deg = 10320 blocks
  k_initc<<<10320, 256, 0, stream>>>(node_h, w_init, b_init, hA8, w_fc, w_fc2, w_fc3, Wb, ne, Ane,
                                     dst, deg);
  k_scan_part<<<98, 256, 0, stream>>>(deg, part);
  k_scan_mid<<<1, 128, 0, stream>>>(part, 98, offs);
  k_scan_apply<<<98, 256, 0, stream>>>(deg, part, offs, cursor);
  k_fill<<<(NE + 255) / 256, 256, 0, stream>>>(src, dst, cursor, nsrc);

  // layer 1: x1(fp8) = gin(h0 fp8); stats(g1)
  k_gin<0, 1><<<2048, 256, 0, stream>>>(hA8, offs, nsrc, s_g1, q_g1, g1, be1, (void*)hX8, s_g1, q_g1);
  // layer 2: x2(fp8, reuses h0 buffer) = gin(relu(bn1(x1))); stats(g2)
  k_gin<1, 1><<<2048, 256, 0, stream>>>(hX8, offs, nsrc, s_g1, q_g1, g1, be1, (void*)hA8, s_g2, q_g2);

  // pool over relu(bn2(x2))
  k_poolbn<<<NGRAPH, 256, 0, stream>>>(hA8, ngr, s_g2, q_g2, g2, be2, qemb);

  // P1 = [qemb|pg] @ Wtop + bias
  dim3 gq(16, 4);
  k_gemm<0, 0, 2><<<gq, 256, 0, stream>>>((const void*)qemb, pg, Wq, b_fc, nullptr,
                                          nullptr, nullptr, nullptr, nullptr,
                                          (void*)P1, s_f1, q_f1, 1024);
  dim3 gg(160, 4);
  // X1 = Ane @ Wbot + P1[row/KREP]
  k_gemm<2, 0, 0><<<gg, 256, 0, stream>>>((const void*)Ane, nullptr, Wbot, nullptr, P1,
                                          nullptr, nullptr, nullptr, nullptr,
                                          (void*)X1, s_f1, q_f1, 512);
  // X2 = relu(bn(X1)) @ W2 + b2
  k_gemm<1, 1, 0><<<gg, 256, 0, stream>>>((const void*)X1, nullptr, Wb2, b_fc2, nullptr,
                                          s_f1, q_f1, gb, bb,
                                          (void*)X2, s_f2, q_f2, 256);
  // X3 = relu(bn(X2)) @ W3 + b3
  k_gemm<1, 1, 0><<<gg, 256, 0, stream>>>((const void*)X2, nullptr, Wb3, b_fc3, nullptr,
                                          s_f2, q_f2, gb2, bb2,
                                          (void*)X3, s_f3, q_f3, 256);
  k_bnfc4<<<1280, 256, 0, stream>>>(X3, s_f3, q_f3, gb3, bb3, w_fc4, b_fc4, H3, preds);
}